// Round 5
// baseline (35.992 us; speedup 1.0000x reference)
//
#include <hip/hip_runtime.h>

#define TT 256
#define HH 512
#define WW 512
#define LOG2E 1.44269504088896340736f
#define KS (100.0f * LOG2E)
#define STEP (1.0f / 511.0f)
#define RUN 8      // consecutive y-pixels per thread (4 A/B pairs)
#define CHUNK 32   // triangles per wave (8 waves cover all 256)

typedef float f2 __attribute__((ext_vector_type(2)));

static __device__ __forceinline__ f2 pk_fma(f2 a, f2 b, f2 c) {
    f2 d;
    asm("v_pk_fma_f32 %0, %1, %2, %3" : "=v"(d) : "v"(a), "v"(b), "v"(c));
    return d;
}
static __device__ __forceinline__ f2 pk_mul(f2 a, f2 b) {
    f2 d;
    asm("v_pk_mul_f32 %0, %1, %2" : "=v"(d) : "v"(a), "v"(b));
    return d;
}
static __device__ __forceinline__ f2 pk_add(f2 a, f2 b) {
    f2 d;
    asm("v_pk_add_f32 %0, %1, %2" : "=v"(d) : "v"(a), "v"(b));
    return d;
}

// ws layout (floats):
//  [0 .. 16*TT)   : per-triangle 16-float record
//    {Dy0,Dx0,C0, Dy1,Dx1,C1, Dy2,Dx2,C2, k0,k1,k2, expd, expd*cr, expd*cg, expd*cb}
//    E_i(x,y) = x*Dy_i - y*Dx_i + C_i (pre-scaled by SHARPNESS*log2e)
//    u_i = 2^-E_i ; y -> y+STEP multiplies u_i by k_i = 2^(STEP*Dx_i)
//  [16*TT .. +4)  : eps baseline (S, Sr, Sg, Sb)
__global__ __launch_bounds__(256) void tri_setup(
        const float* __restrict__ verts,
        const float* __restrict__ colors,
        const float* __restrict__ depth,
        float* __restrict__ ws) {
    int t = threadIdx.x;

    float v0x = verts[t * 6 + 0], v0y = verts[t * 6 + 1];
    float v1x = verts[t * 6 + 2], v1y = verts[t * 6 + 3];
    float v2x = verts[t * 6 + 4], v2y = verts[t * 6 + 5];

    float dx0 = v1x - v0x, dy0 = v1y - v0y;
    float dx1 = v2x - v1x, dy1 = v2y - v1y;
    float dx2 = v0x - v2x, dy2 = v0y - v2y;
    float c0 = v0y * dx0 - v0x * dy0;
    float c1 = v1y * dx1 - v1x * dy1;
    float c2 = v2y * dx2 - v2x * dy2;

    float expd = __builtin_amdgcn_exp2f(depth[t] * LOG2E);
    float cr = colors[t * 3 + 0], cg = colors[t * 3 + 1], cb = colors[t * 3 + 2];
    float ecr = expd * cr, ecg = expd * cg, ecb = expd * cb;

    float* f = ws + t * 16;
    f[0] = KS * dy0;  f[1] = KS * dx0;  f[2] = KS * c0;
    f[3] = KS * dy1;  f[4] = KS * dx1;  f[5] = KS * c1;
    f[6] = KS * dy2;  f[7] = KS * dx2;  f[8] = KS * c2;
    f[9]  = __builtin_amdgcn_exp2f(STEP * (KS * dx0));
    f[10] = __builtin_amdgcn_exp2f(STEP * (KS * dx1));
    f[11] = __builtin_amdgcn_exp2f(STEP * (KS * dx2));
    f[12] = expd; f[13] = ecr; f[14] = ecg; f[15] = ecb;

    // deterministic single-pass float4 tree reduction of the eps baseline
    __shared__ float4 red[256];
    red[t] = make_float4(expd * 1e-6f, ecr * 1e-6f, ecg * 1e-6f, ecb * 1e-6f);
    __syncthreads();
    for (int s = 128; s > 0; s >>= 1) {
        if (t < s) {
            float4 a = red[t], b = red[t + s];
            red[t] = make_float4(a.x + b.x, a.y + b.y, a.z + b.z, a.w + b.w);
        }
        __syncthreads();
    }
    if (t == 0) {
        ws[16 * TT + 0] = red[0].x;
        ws[16 * TT + 1] = red[0].y;
        ws[16 * TT + 2] = red[0].z;
        ws[16 * TT + 3] = red[0].w;
    }
}

__global__ __launch_bounds__(512, 4) void tri_render(
        const float* __restrict__ ws,
        float* __restrict__ out) {
    __shared__ float4 s_part[4][RUN][64];   // 32 KiB

    int tid  = threadIdx.x;
    int lane = tid & 63;
    int wave = __builtin_amdgcn_readfirstlane(tid >> 6);

    int bx = blockIdx.x & 7;    // 8 x-strips of 64
    int by = blockIdx.x >> 3;   // 64 y-runs of 8

    float px  = (float)(bx * 64 + lane) * STEP;
    float py0 = (float)(by * RUN) * STEP;

    // ACC[pair][channel] = {value at row 2*pair, value at row 2*pair+1}
    f2 ACC[RUN / 2][4];
    #pragma unroll
    for (int i = 0; i < RUN / 2; ++i)
        #pragma unroll
        for (int c = 0; c < 4; ++c)
            ACC[i][c] = (f2){0.0f, 0.0f};

    const f2 ONES = {1.0f, 1.0f};
    const float* tbase = ws + wave * (CHUNK * 16);

    #pragma unroll 2
    for (int j = 0; j < CHUNK; ++j) {
        const float* tp = tbase + (j << 4);
        float Dy0 = tp[0],  Dx0 = tp[1],  C0 = tp[2];
        float Dy1 = tp[3],  Dx1 = tp[4],  C1 = tp[5];
        float Dy2 = tp[6],  Dx2 = tp[7],  C2 = tp[8];

        // u_i = 2^(n_i) at (px, py0); n = -E = py*Dx - px*Dy - C
        float n0 = fmaf(py0, Dx0, -C0);  n0 = fmaf(-px, Dy0, n0);
        float n1 = fmaf(py0, Dx1, -C1);  n1 = fmaf(-px, Dy1, n1);
        float n2 = fmaf(py0, Dx2, -C2);  n2 = fmaf(-px, Dy2, n2);

        // Far-outside skip: mask < 2^-(nmax-1) over the whole 8-row run
        // (|dn/row| <= 7*STEP*|Dx| <= 1). Contribution < 2.8*2^-33 -> drop.
        float nmax = fmaxf(fmaxf(n0, n1), n2);
        if (__all(nmax > 34.0f)) continue;

        float k0 = tp[9], k1 = tp[10], k2 = tp[11];
        float uA0 = __builtin_amdgcn_exp2f(n0);
        float uA1 = __builtin_amdgcn_exp2f(n1);
        float uA2 = __builtin_amdgcn_exp2f(n2);

        f2 U0 = {uA0, uA0 * k0};
        f2 U1 = {uA1, uA1 * k1};
        f2 U2 = {uA2, uA2 * k2};
        float kk0 = k0 * k0, kk1 = k1 * k1, kk2 = k2 * k2;
        f2 K0 = {kk0, kk0};
        f2 K1 = {kk1, kk1};
        f2 K2 = {kk2, kk2};

        float expd = tp[12], ecr = tp[13], ecg = tp[14], ecb = tp[15];
        f2 VE = {expd, expd};
        f2 VR = {ecr, ecr};
        f2 VG = {ecg, ecg};
        f2 VB = {ecb, ecb};

        #pragma unroll
        for (int i = 0; i < RUN / 2; ++i) {
            f2 A1 = pk_add(U1, ONES);          // {1+u1A, 1+u1B}
            f2 P  = pk_fma(U0, A1, A1);        // (1+u0)(1+u1)
            P     = pk_fma(U2, P, P);          // *(1+u2)
            // clamp: also rescues fma(0,inf,inf)=NaN -> 1e18 (correct limit)
            float PA = fminf(P.x, 1e18f);
            float PB = fminf(P.y, 1e18f);
            float rinv = __builtin_amdgcn_rcpf(PA * PB);   // one rcp / 2 px
            f2 W = {rinv * PB, rinv * PA};     // {1/PA, 1/PB} = masks

            ACC[i][0] = pk_fma(W, VE, ACC[i][0]);
            ACC[i][1] = pk_fma(W, VR, ACC[i][1]);
            ACC[i][2] = pk_fma(W, VG, ACC[i][2]);
            ACC[i][3] = pk_fma(W, VB, ACC[i][3]);

            if (i != RUN / 2 - 1) {            // advance 2 rows
                U0 = pk_mul(U0, K0);
                U1 = pk_mul(U1, K1);
                U2 = pk_mul(U2, K2);
            }
        }
    }

    // two-stage deterministic reduction across the 8 waves
    if (wave >= 4) {
        #pragma unroll
        for (int i = 0; i < RUN / 2; ++i) {
            s_part[wave - 4][2 * i][lane] =
                make_float4(ACC[i][0].x, ACC[i][1].x, ACC[i][2].x, ACC[i][3].x);
            s_part[wave - 4][2 * i + 1][lane] =
                make_float4(ACC[i][0].y, ACC[i][1].y, ACC[i][2].y, ACC[i][3].y);
        }
    }
    __syncthreads();
    if (wave < 4) {
        #pragma unroll
        for (int i = 0; i < RUN / 2; ++i) {
            float4 v = s_part[wave][2 * i][lane];
            v.x += ACC[i][0].x; v.y += ACC[i][1].x;
            v.z += ACC[i][2].x; v.w += ACC[i][3].x;
            s_part[wave][2 * i][lane] = v;
            float4 w = s_part[wave][2 * i + 1][lane];
            w.x += ACC[i][0].y; w.y += ACC[i][1].y;
            w.z += ACC[i][2].y; w.w += ACC[i][3].y;
            s_part[wave][2 * i + 1][lane] = w;
        }
    }
    __syncthreads();

    // finalize: 512 threads -> 512 pixels
    const float* base = ws + 16 * TT;
    float b0 = base[0], b1 = base[1], b2 = base[2], b3 = base[3];

    int i = tid >> 6, l = tid & 63;
    float4 v0 = s_part[0][i][l];
    float4 v1 = s_part[1][i][l];
    float4 v2 = s_part[2][i][l];
    float4 v3 = s_part[3][i][l];
    float sum = b0 + ((v0.x + v1.x) + (v2.x + v3.x));
    float r   = b1 + ((v0.y + v1.y) + (v2.y + v3.y));
    float g   = b2 + ((v0.z + v1.z) + (v2.z + v3.z));
    float bch = b3 + ((v0.w + v1.w) + (v2.w + v3.w));
    float inv = 1.0f / sum;
    int gy = by * RUN + i;
    int gx = bx * 64 + l;
    int pix = gy * WW + gx;
    out[pix]               = r   * inv;
    out[HH * WW + pix]     = g   * inv;
    out[2 * HH * WW + pix] = bch * inv;
}

extern "C" void kernel_launch(void* const* d_in, const int* in_sizes, int n_in,
                              void* d_out, int out_size, void* d_ws, size_t ws_size,
                              hipStream_t stream) {
    const float* verts  = (const float*)d_in[0];
    const float* colors = (const float*)d_in[1];
    const float* depth  = (const float*)d_in[2];
    float* out = (float*)d_out;
    float* ws  = (float*)d_ws;   // 16 KiB + 16 B

    tri_setup<<<dim3(1), dim3(256), 0, stream>>>(verts, colors, depth, ws);
    tri_render<<<dim3((WW / 64) * (HH / RUN)), dim3(512), 0, stream>>>(ws, out);
}

// Round 6
// 34.672 us; speedup vs baseline: 1.0381x; 1.0381x over previous
//
#include <hip/hip_runtime.h>

#define TT 256
#define HH 512
#define WW 512
#define LOG2E 1.44269504088896340736f
#define KS (100.0f * LOG2E)
#define STEP (1.0f / 511.0f)
#define RUN 8      // consecutive y-pixels per thread (4 A/B pairs)
#define CHUNK 16   // triangles per wave (16 waves cover all 256)

// ws layout (floats):
//  [0 .. 16*TT)   : per-triangle 16-float record
//    {Dy0,Dx0,C0, Dy1,Dx1,C1, Dy2,Dx2,C2, k0,k1,k2, expd, expd*cr, expd*cg, expd*cb}
//    E_i(x,y) = x*Dy_i - y*Dx_i + C_i (pre-scaled by SHARPNESS*log2e)
//    u_i = 2^-E_i ; y -> y+STEP multiplies u_i by k_i = 2^(STEP*Dx_i)
//  [16*TT .. +4)  : eps baseline (S, Sr, Sg, Sb)
__global__ __launch_bounds__(256) void tri_setup(
        const float* __restrict__ verts,
        const float* __restrict__ colors,
        const float* __restrict__ depth,
        float* __restrict__ ws) {
    int t = threadIdx.x;

    float v0x = verts[t * 6 + 0], v0y = verts[t * 6 + 1];
    float v1x = verts[t * 6 + 2], v1y = verts[t * 6 + 3];
    float v2x = verts[t * 6 + 4], v2y = verts[t * 6 + 5];

    float dx0 = v1x - v0x, dy0 = v1y - v0y;
    float dx1 = v2x - v1x, dy1 = v2y - v1y;
    float dx2 = v0x - v2x, dy2 = v0y - v2y;
    float c0 = v0y * dx0 - v0x * dy0;
    float c1 = v1y * dx1 - v1x * dy1;
    float c2 = v2y * dx2 - v2x * dy2;

    float expd = __builtin_amdgcn_exp2f(depth[t] * LOG2E);
    float cr = colors[t * 3 + 0], cg = colors[t * 3 + 1], cb = colors[t * 3 + 2];
    float ecr = expd * cr, ecg = expd * cg, ecb = expd * cb;

    float* f = ws + t * 16;
    f[0] = KS * dy0;  f[1] = KS * dx0;  f[2] = KS * c0;
    f[3] = KS * dy1;  f[4] = KS * dx1;  f[5] = KS * c1;
    f[6] = KS * dy2;  f[7] = KS * dx2;  f[8] = KS * c2;
    f[9]  = __builtin_amdgcn_exp2f(STEP * (KS * dx0));
    f[10] = __builtin_amdgcn_exp2f(STEP * (KS * dx1));
    f[11] = __builtin_amdgcn_exp2f(STEP * (KS * dx2));
    f[12] = expd; f[13] = ecr; f[14] = ecg; f[15] = ecb;

    // deterministic single-pass float4 tree reduction of the eps baseline
    __shared__ float4 red[256];
    red[t] = make_float4(expd * 1e-6f, ecr * 1e-6f, ecg * 1e-6f, ecb * 1e-6f);
    __syncthreads();
    for (int s = 128; s > 0; s >>= 1) {
        if (t < s) {
            float4 a = red[t], b = red[t + s];
            red[t] = make_float4(a.x + b.x, a.y + b.y, a.z + b.z, a.w + b.w);
        }
        __syncthreads();
    }
    if (t == 0) {
        ws[16 * TT + 0] = red[0].x;
        ws[16 * TT + 1] = red[0].y;
        ws[16 * TT + 2] = red[0].z;
        ws[16 * TT + 3] = red[0].w;
    }
}

__global__ __launch_bounds__(1024, 8) void tri_render(
        const float* __restrict__ ws,
        float* __restrict__ out) {
    __shared__ float4 s_part[8][RUN][64];   // 64 KiB

    int tid  = threadIdx.x;
    int lane = tid & 63;
    int wave = __builtin_amdgcn_readfirstlane(tid >> 6);   // 0..15

    int bx = blockIdx.x & 7;    // 8 x-strips of 64
    int by = blockIdx.x >> 3;   // 64 y-runs of 8

    float px  = (float)(bx * 64 + lane) * STEP;
    float py0 = (float)(by * RUN) * STEP;

    float acc[RUN][4];
    #pragma unroll
    for (int i = 0; i < RUN; ++i) {
        acc[i][0] = 0.0f; acc[i][1] = 0.0f; acc[i][2] = 0.0f; acc[i][3] = 0.0f;
    }

    const float* tbase = ws + wave * (CHUNK * 16);

    #pragma unroll 2
    for (int j = 0; j < CHUNK; ++j) {
        const float* tp = tbase + (j << 4);
        float Dy0 = tp[0],  Dx0 = tp[1],  C0 = tp[2];
        float Dy1 = tp[3],  Dx1 = tp[4],  C1 = tp[5];
        float Dy2 = tp[6],  Dx2 = tp[7],  C2 = tp[8];

        // u_i = 2^(n_i) at (px, py0); n = -E = py*Dx - px*Dy - C
        float n0 = fmaf(py0, Dx0, -C0);  n0 = fmaf(-px, Dy0, n0);
        float n1 = fmaf(py0, Dx1, -C1);  n1 = fmaf(-px, Dy1, n1);
        float n2 = fmaf(py0, Dx2, -C2);  n2 = fmaf(-px, Dy2, n2);

        // Far-outside skip: over the 8-row run |dn/row| <= 7*STEP*|Dx|*KS <= 1,
        // so nmax>34 everywhere => mask < ~2^-33 for the whole run -> drop.
        float nmax = fmaxf(fmaxf(n0, n1), n2);
        if (__all(nmax > 34.0f)) continue;

        float u0 = __builtin_amdgcn_exp2f(n0);
        float u1 = __builtin_amdgcn_exp2f(n1);
        float u2 = __builtin_amdgcn_exp2f(n2);
        float k0 = tp[9], k1 = tp[10], k2 = tp[11];          // wave-uniform (SGPR)
        float ce = tp[12], cr = tp[13], cg = tp[14], cb = tp[15];

        #pragma unroll
        for (int i = 0; i < RUN / 2; ++i) {
            // pixel A at y-row 2i
            float a  = u1 + 1.0f;
            float PA = fmaf(u0, a, a);      // (1+u0)(1+u1)
            PA = fmaf(u2, PA, PA);          // *(1+u2)
            PA = fminf(PA, 1e18f);          // overflow/NaN guard (min picks 1e18)
            u0 *= k0; u1 *= k1; u2 *= k2;   // advance one row
            // pixel B at y-row 2i+1
            a = u1 + 1.0f;
            float PB = fmaf(u0, a, a);
            PB = fmaf(u2, PB, PB);
            PB = fminf(PB, 1e18f);
            if (i != RUN / 2 - 1) { u0 *= k0; u1 *= k1; u2 *= k2; }

            float rinv = __builtin_amdgcn_rcpf(PA * PB);   // one rcp / 2 px
            float wA = rinv * PB;           // mask_A
            float wB = rinv * PA;           // mask_B

            acc[2*i][0]   = fmaf(wA, ce, acc[2*i][0]);
            acc[2*i+1][0] = fmaf(wB, ce, acc[2*i+1][0]);
            acc[2*i][1]   = fmaf(wA, cr, acc[2*i][1]);
            acc[2*i+1][1] = fmaf(wB, cr, acc[2*i+1][1]);
            acc[2*i][2]   = fmaf(wA, cg, acc[2*i][2]);
            acc[2*i+1][2] = fmaf(wB, cg, acc[2*i+1][2]);
            acc[2*i][3]   = fmaf(wA, cb, acc[2*i][3]);
            acc[2*i+1][3] = fmaf(wB, cb, acc[2*i+1][3]);
        }
    }

    // two-stage deterministic reduction across the 16 waves
    if (wave >= 8) {
        #pragma unroll
        for (int i = 0; i < RUN; ++i)
            s_part[wave - 8][i][lane] =
                make_float4(acc[i][0], acc[i][1], acc[i][2], acc[i][3]);
    }
    __syncthreads();
    if (wave < 8) {
        #pragma unroll
        for (int i = 0; i < RUN; ++i) {
            float4 v = s_part[wave][i][lane];
            v.x += acc[i][0]; v.y += acc[i][1];
            v.z += acc[i][2]; v.w += acc[i][3];
            s_part[wave][i][lane] = v;
        }
    }
    __syncthreads();

    // finalize: first 512 threads -> 512 pixels
    if (tid < 512) {
        const float* base = ws + 16 * TT;
        float b0 = base[0], b1 = base[1], b2 = base[2], b3 = base[3];

        int i = tid >> 6, l = tid & 63;
        float4 v0 = s_part[0][i][l];
        float4 v1 = s_part[1][i][l];
        float4 v2 = s_part[2][i][l];
        float4 v3 = s_part[3][i][l];
        float4 v4 = s_part[4][i][l];
        float4 v5 = s_part[5][i][l];
        float4 v6 = s_part[6][i][l];
        float4 v7 = s_part[7][i][l];
        float sum = b0 + (((v0.x + v1.x) + (v2.x + v3.x)) + ((v4.x + v5.x) + (v6.x + v7.x)));
        float r   = b1 + (((v0.y + v1.y) + (v2.y + v3.y)) + ((v4.y + v5.y) + (v6.y + v7.y)));
        float g   = b2 + (((v0.z + v1.z) + (v2.z + v3.z)) + ((v4.z + v5.z) + (v6.z + v7.z)));
        float bch = b3 + (((v0.w + v1.w) + (v2.w + v3.w)) + ((v4.w + v5.w) + (v6.w + v7.w)));
        float inv = 1.0f / sum;
        int gy = by * RUN + i;
        int gx = bx * 64 + l;
        int pix = gy * WW + gx;
        out[pix]               = r   * inv;
        out[HH * WW + pix]     = g   * inv;
        out[2 * HH * WW + pix] = bch * inv;
    }
}

extern "C" void kernel_launch(void* const* d_in, const int* in_sizes, int n_in,
                              void* d_out, int out_size, void* d_ws, size_t ws_size,
                              hipStream_t stream) {
    const float* verts  = (const float*)d_in[0];
    const float* colors = (const float*)d_in[1];
    const float* depth  = (const float*)d_in[2];
    float* out = (float*)d_out;
    float* ws  = (float*)d_ws;   // 16 KiB + 16 B

    tri_setup<<<dim3(1), dim3(256), 0, stream>>>(verts, colors, depth, ws);
    tri_render<<<dim3((WW / 64) * (HH / RUN)), dim3(1024), 0, stream>>>(ws, out);
}